// Round 10
// baseline (131.869 us; speedup 1.0000x reference)
//
#include <hip/hip_runtime.h>

// FlowNetC correlation, B=16 C=256 H=48 W=64, 21x21 displacements (stride 2, +/-20).
// out[b, i*21+j, h, w] = sum_c in1[b,c,h,w] * in2[b,c,h+2i-20,w+2j-20]  (zero OOB)
//
// v10 = v9 with the register pins done per 32-bit COMPONENT (uint4 "+v" ties
// are unsupported: "tied indirect register inputs"). Strategy unchanged:
//  - rotated B pipeline: oy's MFMAs consume q[]; oy+1's 16 loads overwrite q[]
//    after, pinned above SCAT/barrier/COPYOUT by asm volatile("" ::: "memory").
//    The barrier's bulk vmcnt(0) drains them once, covered by SCAT+copyout.
//  - asm component pins force av[16] (64 VGPR) + q[16] (64 VGPR) to stay live:
//    blocks the rematerialize/sink that kept VGPR at 84 in v6-v8.

#define NB 16
#define NC 256
#define NH 48
#define NW 64
#define HW (NH * NW)
#define CHW (NC * NH * NW)
#define ND 21
#define NDISP (ND * ND)

typedef __fp16 half2v __attribute__((ext_vector_type(2)));
typedef _Float16 f16x8 __attribute__((ext_vector_type(8)));
typedef float f32x16 __attribute__((ext_vector_type(16)));

__device__ __forceinline__ unsigned pk2(float lo, float hi) {
    half2v h = __builtin_amdgcn_cvt_pkrtz(lo, hi);
    return __builtin_bit_cast(unsigned, h);
}
__device__ __forceinline__ half2v uph(unsigned u) {
    return __builtin_bit_cast(half2v, u);
}

#define PIN4(v_) asm volatile("" : "+v"((v_).x), "+v"((v_).y), "+v"((v_).z), "+v"((v_).w))

// ---------------- Kernel T: transpose + pack (LDS-staged) ----------------
// src [b][c 256][h][w 64] f32 -> dst [(b_local*48+h)*2+par][w' 32][c2 128] u32
__global__ __launch_bounds__(256, 4)
void transpose_pack(const float* __restrict__ in1,
                    const float* __restrict__ in2,
                    unsigned* __restrict__ t1,
                    unsigned* __restrict__ t2,
                    int b_base, int nwg48) {
    __shared__ unsigned xs[64 * 129];        // [w 64][c2 128 +1 pad] -> conflict-free
    const int bx = blockIdx.x;
    const int which = (bx >= nwg48) ? 1 : 0;
    const int r = bx - which * nwg48;
    const int b_local = r / NH;
    const int h = r % NH;
    const float* src = (which ? in2 : in1) + (size_t)(b_base + b_local) * CHW + (size_t)h * NW;
    unsigned* dst = (which ? t2 : t1) + (size_t)((b_local * NH + h) * 2) * 4096;

    const int t = threadIdx.x;
    const int w = t & 63;
    const int c2b = t >> 6;                  // 0..3

    #pragma unroll 8
    for (int it = 0; it < 32; ++it) {
        const int c2 = c2b * 32 + it;
        const float lo = src[(size_t)(2 * c2) * HW + w];
        const float hi = src[(size_t)(2 * c2 + 1) * HW + w];
        xs[w * 129 + c2] = pk2(lo, hi);
    }
    __syncthreads();
    #pragma unroll 8
    for (int it = 0; it < 32; ++it) {
        const int k = t + 256 * it;          // 0..8191
        const int c2 = k & 127;
        const int wp = k >> 7;               // par = wp>>5, w' = wp&31
        dst[(size_t)(wp >> 5) * 4096 + (size_t)(wp & 31) * 128 + c2] =
            xs[(2 * (wp & 31) + (wp >> 5)) * 129 + c2];
    }
}

// ---------------- Kernel 2: banded-Gram MFMA, pinned rotated pipeline ----------------
// slab region per oy: [par 2][j 21][34] = 1428 floats; dbuf = 2856 (11.4 KB).
__global__ __launch_bounds__(256, 3)
void corr_mfma(const unsigned* __restrict__ in1T, const unsigned* __restrict__ in2T,
               float* __restrict__ out, int b_base, int nbh) {
    __shared__ float slab[2856];

    const int t = threadIdx.x;
    const int lane = t & 63;
    const int wid = t >> 6;
    const int par = wid >> 1;
    const int nt = wid & 1;
    const int ln31 = lane & 31;
    const int kh = lane >> 5;

    const int bx = blockIdx.x;
    const int cpx = nbh >> 3;               // nbh = bc*48, divisible by 8
    const int L = (bx & 7) * cpx + (bx >> 3);
    const int b_local = L / NH;
    const int h = L % NH;
    const int b = b_base + b_local;

    float* out_b = out + (size_t)b * NDISP * HW + (size_t)h * NW;

    // B-lane geometry: w2' = nt*32 - 16 + ln31 (parity-plane column), zero OOB
    const int w2p = nt * 32 - 16 + ln31;
    const bool bval = ((unsigned)w2p < 32u);
    const int w2c = bval ? w2p : 0;

    const int lo = (h >= 20) ? 0 : ((21 - h) >> 1);
    const int hi = min(20, (67 - h) >> 1);

    // zero slabs for OOB oy rows
    #pragma unroll 1
    for (int oy = 0; oy < ND; ++oy) {
        if (oy >= lo && oy <= hi) continue;
        #pragma unroll
        for (int s_ = 0; s_ < 6; ++s_) {
            int k_ = t + 256 * s_;
            if (k_ < ND * NW)
                out_b[(size_t)(oy * ND + (k_ >> 6)) * HW + (k_ & 63)] = 0.f;
        }
    }

    // ---- A-frags to registers (once per block), pinned against remat ----
    const unsigned* pa = in1T +
        ((size_t)((b_local * NH + h) * 2 + par)) * 4096 + (size_t)ln31 * 128 + kh * 4;
    uint4 av[16];
    #pragma unroll
    for (int kk = 0; kk < 16; ++kk) av[kk] = *(const uint4*)(pa + 8 * kk);
    #pragma unroll
    for (int kk = 0; kk < 16; ++kk) PIN4(av[kk]);

#define PB(oy_) (in2T + ((size_t)((b_local * NH + (h + 2 * (oy_) - 20)) * 2 + par)) * 4096 + \
                 (size_t)w2c * 128 + kh * 4)

#define SCAT(region_, acc_)                                                   \
    do {                                                                      \
        _Pragma("unroll") for (int r_ = 0; r_ < 16; ++r_) {                   \
            const int m_ = (r_ & 3) + 8 * (r_ >> 2) + 4 * kh;                 \
            const int j_ = 32 * nt + ln31 - m_ - 6;                           \
            if ((unsigned)j_ < (unsigned)ND)                                  \
                (region_)[par * 714 + j_ * 34 + m_] = acc_[r_];               \
        }                                                                     \
    } while (0)

#define COPYOUT(oy_, region_)                                                 \
    do {                                                                      \
        _Pragma("unroll") for (int s_ = 0; s_ < 6; ++s_) {                    \
            int k_ = t + 256 * s_;                                            \
            if (k_ < ND * NW) {                                               \
                int j_ = k_ >> 6, w_ = k_ & 63;                               \
                out_b[(size_t)((oy_)*ND + j_) * HW + w_] =                    \
                    (region_)[(w_ & 1) * 714 + j_ * 34 + (w_ >> 1)];          \
            }                                                                 \
        }                                                                     \
    } while (0)

    // prologue: issue oy=lo's 16 B-loads RAW (clamped address; zeroing at consume)
    uint4 q[16];
    {
        const unsigned* pb = PB(lo);
        #pragma unroll
        for (int kk = 0; kk < 16; ++kk) q[kk] = *(const uint4*)(pb + 8 * kk);
    }
    asm volatile("" ::: "memory");           // loads may not sink below here

    int buf = 0;
    #pragma unroll 1
    for (int oy = lo; oy <= hi; ++oy, buf ^= 1) {
        // pin q: 16 distinct live VGPR quads, values ready (drained at prev barrier)
        #pragma unroll
        for (int kk = 0; kk < 16; ++kk) PIN4(q[kk]);

        f32x16 acc;
        #pragma unroll
        for (int i = 0; i < 16; ++i) acc[i] = 0.f;

        __builtin_amdgcn_s_setprio(1);
        #pragma unroll
        for (int kk = 0; kk < 16; ++kk) {
            uint4 qq;
            qq.x = bval ? q[kk].x : 0u;       // cndmask at consume site
            qq.y = bval ? q[kk].y : 0u;
            qq.z = bval ? q[kk].z : 0u;
            qq.w = bval ? q[kk].w : 0u;
            acc = __builtin_amdgcn_mfma_f32_32x32x16_f16(
                __builtin_bit_cast(f16x8, av[kk]),
                __builtin_bit_cast(f16x8, qq), acc, 0, 0, 0);
        }
        __builtin_amdgcn_s_setprio(0);

        // rotate: issue NEXT oy's loads into q; the memory clobber below stops
        // the scheduler from sinking them past SCAT/barrier/COPYOUT. They drain
        // in ONE bulk vmcnt(0) at the barrier, covered by SCAT.
        if (oy + 1 <= hi) {
            const unsigned* pb = PB(oy + 1);
            #pragma unroll
            for (int kk = 0; kk < 16; ++kk) q[kk] = *(const uint4*)(pb + 8 * kk);
        }
        asm volatile("" ::: "memory");

        float* sb = slab + buf * 1428;
        SCAT(sb, acc);
        __syncthreads();
        COPYOUT(oy, sb);
    }
#undef SCAT
#undef COPYOUT
#undef PB
}

// ---------------- Fallback: v3 dot2 kernel ----------------
#define NCB 16
#define IN1_P 36
#define IN1_C2 (2 * IN1_P)
#define IN1_WORDS (128 * IN1_C2)
#define IN2_P 52
#define IN2_C2 (2 * IN2_P)
#define IN2_WAVE (8 * IN2_C2)
#define LDS_WORDS (IN1_WORDS + 4 * IN2_WAVE)

#if defined(__has_builtin)
#if __has_builtin(__builtin_amdgcn_fdot2)
#define HAVE_FDOT2 1
#endif
#endif
__device__ __forceinline__ float fdot2f(half2v a, half2v b, float c) {
#ifdef HAVE_FDOT2
    return __builtin_amdgcn_fdot2(a, b, c, false);
#else
    return c + (float)a.x * (float)b.x + (float)a.y * (float)b.y;
#endif
}
#define WW(u, m) uph(((m) & 1) ? wn[u][(m) >> 1].y : wn[u][(m) >> 1].x)

__global__ __launch_bounds__(256, 3)
void corr_kernel(const float* __restrict__ in1, const float* __restrict__ in2,
                 float* __restrict__ out) {
    __shared__ __align__(16) unsigned lds[LDS_WORDS];
    unsigned* in1_s = lds;
    const int t = threadIdx.x;
    const int lane = t & 63;
    const int wid = t >> 6;
    const int tw = lane & 7;
    const int oh = (lane >> 3) & 1;
    const int p = (lane >> 4) & 1;
    const int chalf = (lane >> 5) & 1;
    unsigned* in2w = lds + IN1_WORDS + wid * IN2_WAVE;
    const int bx = blockIdx.x;
    const int L = (bx & 7) * 96 + (bx >> 3);
    const int b = L / NH;
    const int h = L % NH;
    const float* in1_row = in1 + (size_t)b * CHW + (size_t)h * NW;
    for (int i = lane; i < IN2_WAVE; i += 64) in2w[i] = 0u;
    #pragma unroll 1
    for (int j = 0; j < 8; ++j) {
        const int task = t + 256 * j;
        const int c2 = task >> 4;
        const int c4 = task & 15;
        const float4 u0 = ((const float4*)(in1_row + (size_t)(2 * c2) * HW))[c4];
        const float4 u1 = ((const float4*)(in1_row + (size_t)(2 * c2 + 1) * HW))[c4];
        unsigned* d0 = &in1_s[c2 * IN1_C2 + 2 * c4];
        *(uint2*)&d0[0] = make_uint2(pk2(u0.x, u1.x), pk2(u0.z, u1.z));
        *(uint2*)&d0[IN1_P] = make_uint2(pk2(u0.y, u1.y), pk2(u0.w, u1.w));
    }
    __syncthreads();
    const int q = lane >> 4;
    const int col4 = lane & 15;
    const int lo = (h >= 20) ? 0 : ((21 - h) >> 1);
    const int hi = min(20, (67 - h) >> 1);
    const int nv = hi - lo + 1;
    const int rot = (wid + h) & 3;
    #pragma unroll 1
    for (int oy = rot; oy < ND; oy += 4) {
        if (oy >= lo && oy <= hi) continue;
        float* orow = out + ((size_t)(b * NDISP + oy * ND) * NH + h) * NW;
        #pragma unroll
        for (int o = 0; o < ND; ++o) orow[(size_t)o * HW + lane] = 0.f;
    }
    #pragma unroll 1
    for (int k = rot; k < nv; k += 4) {
        const int oyi = lo + k;
        const int row = h + 2 * oyi - 20;
        float* orow = out + ((size_t)(b * NDISP + oyi * ND) * NH + h) * NW;
        const float* in2_row = in2 + (size_t)b * CHW + (size_t)row * NW;
        float acc[11][4];
        #pragma unroll
        for (int ol = 0; ol < 11; ++ol)
            #pragma unroll
            for (int i = 0; i < 4; ++i) acc[ol][i] = 0.f;
        float4 pre[4];
        {
            const float* s0 = in2_row + (size_t)(2 * q) * HW;
            const float* s1 = in2_row + (size_t)(2 * (q + 4)) * HW;
            pre[0] = ((const float4*)s0)[col4];
            pre[1] = ((const float4*)(s0 + HW))[col4];
            pre[2] = ((const float4*)s1)[col4];
            pre[3] = ((const float4*)(s1 + HW))[col4];
        }
        #pragma unroll 1
        for (int cb = 0; cb < NCB; ++cb) {
            {
                unsigned* da = &in2w[q * IN2_C2 + 2 * col4 + 10];
                unsigned* db = &in2w[(q + 4) * IN2_C2 + 2 * col4 + 10];
                *(uint2*)&da[0] = make_uint2(pk2(pre[0].x, pre[1].x), pk2(pre[0].z, pre[1].z));
                *(uint2*)&da[IN2_P] = make_uint2(pk2(pre[0].y, pre[1].y), pk2(pre[0].w, pre[1].w));
                *(uint2*)&db[0] = make_uint2(pk2(pre[2].x, pre[3].x), pk2(pre[2].z, pre[3].z));
                *(uint2*)&db[IN2_P] = make_uint2(pk2(pre[2].y, pre[3].y), pk2(pre[2].w, pre[3].w));
            }
            if (cb + 1 < NCB) {
                const float* srcn = in2_row + (size_t)((cb + 1) * 16) * HW;
                const float* s0 = srcn + (size_t)(2 * q) * HW;
                const float* s1 = srcn + (size_t)(2 * (q + 4)) * HW;
                pre[0] = ((const float4*)s0)[col4];
                pre[1] = ((const float4*)(s0 + HW))[col4];
                pre[2] = ((const float4*)s1)[col4];
                pre[3] = ((const float4*)(s1 + HW))[col4];
            }
            uint4 avv[4];
            uint2 wn[4][7];
            {
                const unsigned* base1 = &in1_s[(cb * 8 + chalf) * IN1_C2 + p * IN1_P + 4 * tw];
                const unsigned* base2 = &in2w[chalf * IN2_C2 + p * IN2_P + 4 * tw + 10 * oh];
                #pragma unroll
                for (int u = 0; u < 4; ++u) {
                    avv[u] = *(const uint4*)(base1 + (size_t)(2 * u) * IN1_C2);
                    #pragma unroll
                    for (int jj = 0; jj < 7; ++jj)
                        wn[u][jj] = *(const uint2*)(base2 + (size_t)(2 * u) * IN2_C2 + 2 * jj);
                }
            }
            #pragma unroll
            for (int u = 0; u < 4; ++u) {
                const half2v a0 = uph(avv[u].x), a1 = uph(avv[u].y);
                const half2v a2 = uph(avv[u].z), a3 = uph(avv[u].w);
                #pragma unroll
                for (int ol = 0; ol < 11; ++ol) {
                    acc[ol][0] = fdot2f(a0, WW(u, ol + 0), acc[ol][0]);
                    acc[ol][1] = fdot2f(a1, WW(u, ol + 1), acc[ol][1]);
                    acc[ol][2] = fdot2f(a2, WW(u, ol + 2), acc[ol][2]);
                    acc[ol][3] = fdot2f(a3, WW(u, ol + 3), acc[ol][3]);
                }
            }
        }
        #pragma unroll
        for (int ol = 0; ol < 11; ++ol)
            #pragma unroll
            for (int i = 0; i < 4; ++i) {
                float v = acc[ol][i];
                v += __shfl_xor(v, 32);
                acc[ol][i] = v;
            }
        if (chalf == 0) {
            #pragma unroll
            for (int ol = 0; ol < 11; ++ol) {
                if (oh == 1 && ol == 0) continue;
                const int og = 10 * oh + ol;
                #pragma unroll
                for (int i = 0; i < 4; ++i)
                    orow[(size_t)og * HW + (p + 8 * tw + 2 * i)] = acc[ol][i];
            }
        }
    }
}

// ---------------- host ----------------
extern "C" void kernel_launch(void* const* d_in, const int* in_sizes, int n_in,
                              void* d_out, int out_size, void* d_ws, size_t ws_size,
                              hipStream_t stream) {
    const float* in1 = (const float*)d_in[0];
    const float* in2 = (const float*)d_in[1];
    float* out = (float*)d_out;

    const size_t per_b = 1572864;  // 48*2*32*256*2 bytes
    int bc = 0;
    const int cands[5] = {16, 8, 4, 2, 1};
    for (int i = 0; i < 5; ++i) {
        if ((size_t)cands[i] * 2 * per_b <= ws_size) { bc = cands[i]; break; }
    }
    if (bc == 0) {
        corr_kernel<<<dim3(NB * NH), dim3(256), 0, stream>>>(in1, in2, out);
        return;
    }
    unsigned* t1 = (unsigned*)d_ws;
    unsigned* t2 = t1 + (size_t)bc * NH * 2 * 4096;
    const int nwg48 = bc * NH;
    for (int b0 = 0; b0 < NB; b0 += bc) {
        transpose_pack<<<dim3(2 * nwg48), dim3(256), 0, stream>>>(in1, in2, t1, t2, b0, nwg48);
        corr_mfma<<<dim3(nwg48), dim3(256), 0, stream>>>(t1, t2, out, b0, nwg48);
    }
}

// Round 11
// 82.273 us; speedup vs baseline: 1.6028x; 1.6028x over previous
//
#include <hip/hip_runtime.h>

// FlowNetC correlation, B=16 C=256 H=48 W=64, 21x21 displacements (stride 2, +/-20).
// out[b, i*21+j, h, w] = sum_c in1[b,c,h,w] * in2[b,c,h+2i-20,w+2j-20]  (zero OOB)
//
// v11: B operands via global_load_lds (register-less DMA). v6-v10 proved the
// allocator will not keep a 64-reg B batch live -> 16 serial L2 waits/iter.
// global_load_lds has NO dest VGPR: 8x16B issue back-to-back per wave, drain in
// ONE bulk vmcnt at the barrier, consumed by ds_read_b128 (compiler schedules
// lgkmcnt finely). Single-buffered B plane (32KB) + dbuf slab = 43.4KB LDS ->
// 3 blocks/CU at (256,3); grid 768 = one exact round.
// LDS bank fix: [32][128w] plane read column-wise is 16-way conflicted, so the
// 16B-chunk index is XOR'd with (row&7) -- applied on the per-lane GLOBAL source
// address (global_load_lds writes linearly), and on the ds_read address.

#define NB 16
#define NC 256
#define NH 48
#define NW 64
#define HW (NH * NW)
#define CHW (NC * NH * NW)
#define ND 21
#define NDISP (ND * ND)

typedef __fp16 half2v __attribute__((ext_vector_type(2)));
typedef _Float16 f16x8 __attribute__((ext_vector_type(8)));
typedef float f32x16 __attribute__((ext_vector_type(16)));

__device__ __forceinline__ unsigned pk2(float lo, float hi) {
    half2v h = __builtin_amdgcn_cvt_pkrtz(lo, hi);
    return __builtin_bit_cast(unsigned, h);
}
__device__ __forceinline__ half2v uph(unsigned u) {
    return __builtin_bit_cast(half2v, u);
}

__device__ __forceinline__ void glds16(unsigned* l, const unsigned* g) {
    __builtin_amdgcn_global_load_lds(
        (const __attribute__((address_space(1))) unsigned*)g,
        (__attribute__((address_space(3))) unsigned*)l, 16, 0, 0);
}

// ---------------- Kernel T: transpose + pack (LDS-staged) ----------------
// src [b][c 256][h][w 64] f32 -> dst [(b_local*48+h)*2+par][w' 32][c2 128] u32
__global__ __launch_bounds__(256, 4)
void transpose_pack(const float* __restrict__ in1,
                    const float* __restrict__ in2,
                    unsigned* __restrict__ t1,
                    unsigned* __restrict__ t2,
                    int b_base, int nwg48) {
    __shared__ unsigned xs[64 * 129];        // [w 64][c2 128 +1 pad] -> conflict-free
    const int bx = blockIdx.x;
    const int which = (bx >= nwg48) ? 1 : 0;
    const int r = bx - which * nwg48;
    const int b_local = r / NH;
    const int h = r % NH;
    const float* src = (which ? in2 : in1) + (size_t)(b_base + b_local) * CHW + (size_t)h * NW;
    unsigned* dst = (which ? t2 : t1) + (size_t)((b_local * NH + h) * 2) * 4096;

    const int t = threadIdx.x;
    const int w = t & 63;
    const int c2b = t >> 6;                  // 0..3

    #pragma unroll 8
    for (int it = 0; it < 32; ++it) {
        const int c2 = c2b * 32 + it;
        const float lo = src[(size_t)(2 * c2) * HW + w];
        const float hi = src[(size_t)(2 * c2 + 1) * HW + w];
        xs[w * 129 + c2] = pk2(lo, hi);
    }
    __syncthreads();
    #pragma unroll 8
    for (int it = 0; it < 32; ++it) {
        const int k = t + 256 * it;          // 0..8191
        const int c2 = k & 127;
        const int wp = k >> 7;               // par = wp>>5, w' = wp&31
        dst[(size_t)(wp >> 5) * 4096 + (size_t)(wp & 31) * 128 + c2] =
            xs[(2 * (wp & 31) + (wp >> 5)) * 129 + c2];
    }
}

// ---------------- Kernel 2: banded-Gram MFMA, DMA-staged B ----------------
// bplane[par][32 rows x 128 words] = 32KB; slab dbuf 2x1428 floats = 11.4KB.
__global__ __launch_bounds__(256, 3)
void corr_mfma(const unsigned* __restrict__ in1T, const unsigned* __restrict__ in2T,
               float* __restrict__ out, int b_base, int nbh) {
    __shared__ __align__(16) unsigned bplane[2][4096];
    __shared__ float slab[2856];

    const int t = threadIdx.x;
    const int lane = t & 63;
    const int wid = t >> 6;
    const int par = wid >> 1;
    const int nt = wid & 1;
    const int ln31 = lane & 31;
    const int kh = lane >> 5;

    const int bx = blockIdx.x;
    const int cpx = nbh >> 3;               // nbh = bc*48, divisible by 8
    const int L = (bx & 7) * cpx + (bx >> 3);
    const int b_local = L / NH;
    const int h = L % NH;
    const int b = b_base + b_local;

    float* out_b = out + (size_t)b * NDISP * HW + (size_t)h * NW;

    // B-lane geometry: w2' = nt*32 - 16 + ln31 (parity-plane row), zero OOB
    const int w2p = nt * 32 - 16 + ln31;
    const bool bval = ((unsigned)w2p < 32u);
    const int w2c = bval ? w2p : 0;

    const int lo = (h >= 20) ? 0 : ((21 - h) >> 1);
    const int hi = min(20, (67 - h) >> 1);

    // zero slabs for OOB oy rows
    #pragma unroll 1
    for (int oy = 0; oy < ND; ++oy) {
        if (oy >= lo && oy <= hi) continue;
        #pragma unroll
        for (int s_ = 0; s_ < 6; ++s_) {
            int k_ = t + 256 * s_;
            if (k_ < ND * NW)
                out_b[(size_t)(oy * ND + (k_ >> 6)) * HW + (k_ & 63)] = 0.f;
        }
    }

    // ---- A-frags to registers (once per block) ----
    const unsigned* pa = in1T +
        ((size_t)((b_local * NH + h) * 2 + par)) * 4096 + (size_t)ln31 * 128 + kh * 4;
    uint4 av[16];
    #pragma unroll
    for (int kk = 0; kk < 16; ++kk) av[kk] = *(const uint4*)(pa + 8 * kk);

#define SCAT(region_, acc_)                                                   \
    do {                                                                      \
        _Pragma("unroll") for (int r_ = 0; r_ < 16; ++r_) {                   \
            const int m_ = (r_ & 3) + 8 * (r_ >> 2) + 4 * kh;                 \
            const int j_ = 32 * nt + ln31 - m_ - 6;                           \
            if ((unsigned)j_ < (unsigned)ND)                                  \
                (region_)[par * 714 + j_ * 34 + m_] = acc_[r_];               \
        }                                                                     \
    } while (0)

#define COPYOUT(oy_, region_)                                                 \
    do {                                                                      \
        _Pragma("unroll") for (int s_ = 0; s_ < 6; ++s_) {                    \
            int k_ = t + 256 * s_;                                            \
            if (k_ < ND * NW) {                                               \
                int j_ = k_ >> 6, w_ = k_ & 63;                               \
                out_b[(size_t)((oy_)*ND + j_) * HW + w_] =                    \
                    (region_)[(w_ & 1) * 714 + j_ * 34 + (w_ >> 1)];          \
            }                                                                 \
        }                                                                     \
    } while (0)

    const unsigned* gplanes = in2T + ((size_t)(b_local * NH) * 2) * 4096;
    const int rsw = w2c & 7;
    const unsigned* lrow = &bplane[par][0] + w2c * 128;

    int buf = 0;
    #pragma unroll 1
    for (int oy = lo; oy <= hi; ++oy, buf ^= 1) {
        // ---- STAGE: 8x16B DMA per wave, no dest VGPRs ----
        {
            const unsigned* gp = gplanes +
                ((size_t)((h + 2 * oy - 20) * 2 + par)) * 4096;
            unsigned* lp = &bplane[par][0];
            #pragma unroll
            for (int il = 0; il < 8; ++il) {
                const int ip = (nt << 3) + il;        // KB index 0..15
                const int row = (ip << 1) + kh;       // per-lane row (kh)
                // global source pre-swizzled: chunk' = ln31 ^ (row&7)
                glds16(lp + (ip << 8),
                       gp + row * 128 + ((ln31 ^ (row & 7)) << 2));
            }
        }
        __syncthreads();       // ONE bulk vmcnt drain; planes ready

        // ---- compute: ds_read_b128 (swizzled) -> cndmask -> MFMA ----
        f32x16 acc;
        #pragma unroll
        for (int i = 0; i < 16; ++i) acc[i] = 0.f;

        __builtin_amdgcn_s_setprio(1);
        #pragma unroll
        for (int kk = 0; kk < 16; ++kk) {
            const uint4 qv = *(const uint4*)(lrow + (((2 * kk + kh) ^ rsw) << 2));
            uint4 qq;
            qq.x = bval ? qv.x : 0u;
            qq.y = bval ? qv.y : 0u;
            qq.z = bval ? qv.z : 0u;
            qq.w = bval ? qv.w : 0u;
            acc = __builtin_amdgcn_mfma_f32_32x32x16_f16(
                __builtin_bit_cast(f16x8, av[kk]),
                __builtin_bit_cast(f16x8, qq), acc, 0, 0, 0);
        }
        __builtin_amdgcn_s_setprio(0);

        float* sb = slab + buf * 1428;
        SCAT(sb, acc);
        __syncthreads();       // scat visible; all ds_reads done -> plane reusable
        COPYOUT(oy, sb);
    }
#undef SCAT
#undef COPYOUT
}

// ---------------- Fallback: v3 dot2 kernel ----------------
#define NCB 16
#define IN1_P 36
#define IN1_C2 (2 * IN1_P)
#define IN1_WORDS (128 * IN1_C2)
#define IN2_P 52
#define IN2_C2 (2 * IN2_P)
#define IN2_WAVE (8 * IN2_C2)
#define LDS_WORDS (IN1_WORDS + 4 * IN2_WAVE)

#if defined(__has_builtin)
#if __has_builtin(__builtin_amdgcn_fdot2)
#define HAVE_FDOT2 1
#endif
#endif
__device__ __forceinline__ float fdot2f(half2v a, half2v b, float c) {
#ifdef HAVE_FDOT2
    return __builtin_amdgcn_fdot2(a, b, c, false);
#else
    return c + (float)a.x * (float)b.x + (float)a.y * (float)b.y;
#endif
}
#define WW(u, m) uph(((m) & 1) ? wn[u][(m) >> 1].y : wn[u][(m) >> 1].x)

__global__ __launch_bounds__(256, 3)
void corr_kernel(const float* __restrict__ in1, const float* __restrict__ in2,
                 float* __restrict__ out) {
    __shared__ __align__(16) unsigned lds[LDS_WORDS];
    unsigned* in1_s = lds;
    const int t = threadIdx.x;
    const int lane = t & 63;
    const int wid = t >> 6;
    const int tw = lane & 7;
    const int oh = (lane >> 3) & 1;
    const int p = (lane >> 4) & 1;
    const int chalf = (lane >> 5) & 1;
    unsigned* in2w = lds + IN1_WORDS + wid * IN2_WAVE;
    const int bx = blockIdx.x;
    const int L = (bx & 7) * 96 + (bx >> 3);
    const int b = L / NH;
    const int h = L % NH;
    const float* in1_row = in1 + (size_t)b * CHW + (size_t)h * NW;
    for (int i = lane; i < IN2_WAVE; i += 64) in2w[i] = 0u;
    #pragma unroll 1
    for (int j = 0; j < 8; ++j) {
        const int task = t + 256 * j;
        const int c2 = task >> 4;
        const int c4 = task & 15;
        const float4 u0 = ((const float4*)(in1_row + (size_t)(2 * c2) * HW))[c4];
        const float4 u1 = ((const float4*)(in1_row + (size_t)(2 * c2 + 1) * HW))[c4];
        unsigned* d0 = &in1_s[c2 * IN1_C2 + 2 * c4];
        *(uint2*)&d0[0] = make_uint2(pk2(u0.x, u1.x), pk2(u0.z, u1.z));
        *(uint2*)&d0[IN1_P] = make_uint2(pk2(u0.y, u1.y), pk2(u0.w, u1.w));
    }
    __syncthreads();
    const int q = lane >> 4;
    const int col4 = lane & 15;
    const int lo = (h >= 20) ? 0 : ((21 - h) >> 1);
    const int hi = min(20, (67 - h) >> 1);
    const int nv = hi - lo + 1;
    const int rot = (wid + h) & 3;
    #pragma unroll 1
    for (int oy = rot; oy < ND; oy += 4) {
        if (oy >= lo && oy <= hi) continue;
        float* orow = out + ((size_t)(b * NDISP + oy * ND) * NH + h) * NW;
        #pragma unroll
        for (int o = 0; o < ND; ++o) orow[(size_t)o * HW + lane] = 0.f;
    }
    #pragma unroll 1
    for (int k = rot; k < nv; k += 4) {
        const int oyi = lo + k;
        const int row = h + 2 * oyi - 20;
        float* orow = out + ((size_t)(b * NDISP + oyi * ND) * NH + h) * NW;
        const float* in2_row = in2 + (size_t)b * CHW + (size_t)row * NW;
        float acc[11][4];
        #pragma unroll
        for (int ol = 0; ol < 11; ++ol)
            #pragma unroll
            for (int i = 0; i < 4; ++i) acc[ol][i] = 0.f;
        float4 pre[4];
        {
            const float* s0 = in2_row + (size_t)(2 * q) * HW;
            const float* s1 = in2_row + (size_t)(2 * (q + 4)) * HW;
            pre[0] = ((const float4*)s0)[col4];
            pre[1] = ((const float4*)(s0 + HW))[col4];
            pre[2] = ((const float4*)s1)[col4];
            pre[3] = ((const float4*)(s1 + HW))[col4];
        }
        #pragma unroll 1
        for (int cb = 0; cb < NCB; ++cb) {
            {
                unsigned* da = &in2w[q * IN2_C2 + 2 * col4 + 10];
                unsigned* db = &in2w[(q + 4) * IN2_C2 + 2 * col4 + 10];
                *(uint2*)&da[0] = make_uint2(pk2(pre[0].x, pre[1].x), pk2(pre[0].z, pre[1].z));
                *(uint2*)&da[IN2_P] = make_uint2(pk2(pre[0].y, pre[1].y), pk2(pre[0].w, pre[1].w));
                *(uint2*)&db[0] = make_uint2(pk2(pre[2].x, pre[3].x), pk2(pre[2].z, pre[3].z));
                *(uint2*)&db[IN2_P] = make_uint2(pk2(pre[2].y, pre[3].y), pk2(pre[2].w, pre[3].w));
            }
            if (cb + 1 < NCB) {
                const float* srcn = in2_row + (size_t)((cb + 1) * 16) * HW;
                const float* s0 = srcn + (size_t)(2 * q) * HW;
                const float* s1 = srcn + (size_t)(2 * (q + 4)) * HW;
                pre[0] = ((const float4*)s0)[col4];
                pre[1] = ((const float4*)(s0 + HW))[col4];
                pre[2] = ((const float4*)s1)[col4];
                pre[3] = ((const float4*)(s1 + HW))[col4];
            }
            uint4 avv[4];
            uint2 wn[4][7];
            {
                const unsigned* base1 = &in1_s[(cb * 8 + chalf) * IN1_C2 + p * IN1_P + 4 * tw];
                const unsigned* base2 = &in2w[chalf * IN2_C2 + p * IN2_P + 4 * tw + 10 * oh];
                #pragma unroll
                for (int u = 0; u < 4; ++u) {
                    avv[u] = *(const uint4*)(base1 + (size_t)(2 * u) * IN1_C2);
                    #pragma unroll
                    for (int jj = 0; jj < 7; ++jj)
                        wn[u][jj] = *(const uint2*)(base2 + (size_t)(2 * u) * IN2_C2 + 2 * jj);
                }
            }
            #pragma unroll
            for (int u = 0; u < 4; ++u) {
                const half2v a0 = uph(avv[u].x), a1 = uph(avv[u].y);
                const half2v a2 = uph(avv[u].z), a3 = uph(avv[u].w);
                #pragma unroll
                for (int ol = 0; ol < 11; ++ol) {
                    acc[ol][0] = fdot2f(a0, WW(u, ol + 0), acc[ol][0]);
                    acc[ol][1] = fdot2f(a1, WW(u, ol + 1), acc[ol][1]);
                    acc[ol][2] = fdot2f(a2, WW(u, ol + 2), acc[ol][2]);
                    acc[ol][3] = fdot2f(a3, WW(u, ol + 3), acc[ol][3]);
                }
            }
        }
        #pragma unroll
        for (int ol = 0; ol < 11; ++ol)
            #pragma unroll
            for (int i = 0; i < 4; ++i) {
                float v = acc[ol][i];
                v += __shfl_xor(v, 32);
                acc[ol][i] = v;
            }
        if (chalf == 0) {
            #pragma unroll
            for (int ol = 0; ol < 11; ++ol) {
                if (oh == 1 && ol == 0) continue;
                const int og = 10 * oh + ol;
                #pragma unroll
                for (int i = 0; i < 4; ++i)
                    orow[(size_t)og * HW + (p + 8 * tw + 2 * i)] = acc[ol][i];
            }
        }
    }
}

// ---------------- host ----------------
extern "C" void kernel_launch(void* const* d_in, const int* in_sizes, int n_in,
                              void* d_out, int out_size, void* d_ws, size_t ws_size,
                              hipStream_t stream) {
    const float* in1 = (const float*)d_in[0];
    const float* in2 = (const float*)d_in[1];
    float* out = (float*)d_out;

    const size_t per_b = 1572864;  // 48*2*32*256*2 bytes
    int bc = 0;
    const int cands[5] = {16, 8, 4, 2, 1};
    for (int i = 0; i < 5; ++i) {
        if ((size_t)cands[i] * 2 * per_b <= ws_size) { bc = cands[i]; break; }
    }
    if (bc == 0) {
        corr_kernel<<<dim3(NB * NH), dim3(256), 0, stream>>>(in1, in2, out);
        return;
    }
    unsigned* t1 = (unsigned*)d_ws;
    unsigned* t2 = t1 + (size_t)bc * NH * 2 * 4096;
    const int nwg48 = bc * NH;
    for (int b0 = 0; b0 < NB; b0 += bc) {
        transpose_pack<<<dim3(2 * nwg48), dim3(256), 0, stream>>>(in1, in2, t1, t2, b0, nwg48);
        corr_mfma<<<dim3(nwg48), dim3(256), 0, stream>>>(t1, t2, out, b0, nwg48);
    }
}